// Round 7
// baseline (122.913 us; speedup 1.0000x reference)
//
#include <hip/hip_runtime.h>

// Single-head causal attention. Round 7: R6 (8 batches/block, wt staged once
// per block) with the W-staging fixed to 16B-granule wave-region DMA
// (global_load_lds dest is wave-uniform base + lane*size — 12B/stride-24
// violated that and produced NaN).
// B=2048, T=64, C=768, H=64. Inputs fp32: x, Wk, Wq, Wv ([in,out] layout).

#define BATCHES 2048
#define SEQ 64
#define CDIM 768
#define HDIM 64
#define NCHUNK 24  // 768 / 32
#define PB 8       // batches per block

typedef __bf16 bf16x8 __attribute__((ext_vector_type(8)));
typedef float f32x4v __attribute__((ext_vector_type(4)));
typedef unsigned short u16x8 __attribute__((ext_vector_type(8)));

__device__ __forceinline__ unsigned short f2bf(float f) {
  return __builtin_bit_cast(unsigned short, (__bf16)f);
}

// XOR swizzle for 64-elem bf16 parking rows: elem col ^= ((row&7)<<3)
__device__ __forceinline__ int swz(int row, int col) {
  return row * 64 + (col ^ ((row & 7) << 3));
}

__device__ __forceinline__ f32x4v mfma16(bf16x8 a, bf16x8 b, f32x4v c) {
  return __builtin_amdgcn_mfma_f32_16x16x32_bf16(a, b, c, 0, 0, 0);
}

__device__ __forceinline__ bf16x8 lds_frag(const unsigned short* p, int row, int col) {
  return __builtin_bit_cast(bf16x8, *reinterpret_cast<const u16x8*>(p + swz(row, col)));
}

__device__ __forceinline__ void gl_lds16(const void* g, void* l) {
  __builtin_amdgcn_global_load_lds(
      (const __attribute__((address_space(1))) void*)g,
      (__attribute__((address_space(3))) void*)l, 16, 0, 0);
}

// Prep (verified in R4): chunk stride 12288 B, slots 0..767.
// ws element i: c = i/6144, slot = (i%6144)>>3, e = i&7;
// row = slot>>2 (mat*64+h), p = slot&3, g = p^((row>>1)&3), k = c*32+g*8+e.
__global__ __launch_bounds__(256) void prep_wt_kernel(
    const float* __restrict__ Wk, const float* __restrict__ Wq,
    const float* __restrict__ Wv, unsigned short* __restrict__ wt) {
  int i = blockIdx.x * 256 + threadIdx.x;
  if (i >= 3 * HDIM * CDIM) return;
  int c = i / 6144;
  int r2 = i - c * 6144;
  int slot = r2 >> 3;
  int e = r2 & 7;
  int row = slot >> 2;
  int p = slot & 3;
  int g = p ^ ((row >> 1) & 3);
  int k = c * 32 + g * 8 + e;
  int mat = row >> 6;
  int h = row & 63;
  const float* W = (mat == 0) ? Wq : ((mat == 1) ? Wk : Wv);
  wt[i] = f2bf(W[k * HDIM + h]);
}

__global__ __launch_bounds__(512, 2) void head_fused_kernel(
    const float* __restrict__ x, const unsigned short* __restrict__ wt,
    float* __restrict__ out) {
  const int bid = blockIdx.x;        // batches PB*bid .. PB*bid+7
  const int tid = threadIdx.x;
  const int w = tid >> 6;            // wave 0..7
  const int ww = w & 3;              // rows [16ww, 16ww+16)
  const int bat = w >> 2;            // 0/1; slice s -> local batch bat+2s
  const int lane = tid & 63;
  const int lane15 = lane & 15;
  const int lhi = lane >> 4;

  // LDS 152 KB: [xb0 64K @0][xb1 64K @64K][wb0 12K @128K][wb1 12K @140K].
  // Parking rounds alias xb0: region bat*24576: [k 8K][vT 8K][qp 8K].
  __shared__ __align__(16) unsigned char smem[155648];

  // ---- staging addresses ----------------------------------------------------
  // x batch image (8 KB): [row 0..63][phys granule 0..7]x16B; phys granule p
  // holds logical granule p^(row&7) (source pre-swizzled, LDS dest linear:
  // wave-uniform base + lane*16).
  const int xrow = tid >> 3;
  const int xp = tid & 7;
  const char* xbase = (const char*)x + (size_t)(PB * bid) * (SEQ * CDIM * 4) +
                      xrow * (CDIM * 4) + ((xp ^ (xrow & 7)) * 16);
  const int xdst = tid * 16;

  // W chunk = 12 regions x 1KB (64 lanes x 16B). Wave w DMAs region w;
  // waves 0..3 additionally DMA region 8+w. All dests are lane*16-strided.
  const char* wbaseA = (const char*)wt + ((w * 64 + lane) * 16);
  const char* wbaseB = (const char*)wt + (((8 + w) * 64 + lane) * 16);
  const int wdstA = (w * 64 + lane) * 16;
  const int wdstB = ((8 + w) * 64 + lane) * 16;

  #define STAGE_W(cn, B)                                                    \
    do {                                                                    \
      char* wbp = (char*)smem + 131072 + (B) * 12288;                       \
      gl_lds16(wbaseA + (cn) * 12288, wbp + wdstA);                         \
      if (w < 4) gl_lds16(wbaseB + (cn) * 12288, wbp + wdstB);              \
    } while (0)
  #define STAGE_X(cn, B)                                                    \
    do {                                                                    \
      char* xbp = (char*)smem + (B) * 65536;                                \
      _Pragma("unroll")                                                     \
      for (int i = 0; i < PB; ++i)                                          \
        gl_lds16(xbase + (size_t)i * 196608 + (cn) * 128,                   \
                 xbp + i * 8192 + xdst);                                    \
    } while (0)

  const f32x4v z4 = {0.f, 0.f, 0.f, 0.f};
  f32x4v accq[4][4], acck[4][4], accv[4][4];  // [slice][col-frag]
  #pragma unroll
  for (int s = 0; s < 4; ++s)
    #pragma unroll
    for (int n = 0; n < 4; ++n) { accq[s][n] = z4; acck[s][n] = z4; accv[s][n] = z4; }

  const int arow = 16 * ww + lane15;
  const int ag0 = (lhi * 2) ^ (arow & 7);
  const int ag1 = (lhi * 2 + 1) ^ (arow & 7);

  // prologue: 2 chunks in flight. Per-wave queue/chunk: W(2 or 1) + X(8).
  STAGE_W(0, 0);
  STAGE_X(0, 0);
  STAGE_W(1, 1);
  STAGE_X(1, 1);

  #pragma unroll
  for (int c = 0; c < NCHUNK; ++c) {
    // wait own chunk-c loads (chunk c+1's stay in flight), then sync
    if (c < NCHUNK - 1) {
      if (w < 4) asm volatile("s_waitcnt vmcnt(10)" ::: "memory");
      else       asm volatile("s_waitcnt vmcnt(9)" ::: "memory");
    } else {
      asm volatile("s_waitcnt vmcnt(0)" ::: "memory");
    }
    __builtin_amdgcn_s_barrier();

    const char* xb = (const char*)smem + (c & 1) * 65536;
    const unsigned short* wsb =
        (const unsigned short*)((const char*)smem + 131072 + (c & 1) * 12288);

    // A-frags for 4 slices (x read once, cvt once)
    bf16x8 a0, a1, a2, a3;
    #define LOAD_A(s, dst)                                                   \
      do {                                                                   \
        const float* xs = (const float*)(xb + (bat + 2 * (s)) * 8192);       \
        f32x4v xa = *(const f32x4v*)(xs + arow * 32 + ag0 * 4);              \
        f32x4v xb4 = *(const f32x4v*)(xs + arow * 32 + ag1 * 4);             \
        u16x8 ar;                                                            \
        _Pragma("unroll")                                                    \
        for (int i = 0; i < 4; ++i) { ar[i] = f2bf(xa[i]); ar[4 + i] = f2bf(xb4[i]); } \
        dst = __builtin_bit_cast(bf16x8, ar);                                \
      } while (0)
    LOAD_A(0, a0); LOAD_A(1, a1); LOAD_A(2, a2); LOAD_A(3, a3);
    #undef LOAD_A

    #pragma unroll
    for (int n = 0; n < 4; ++n) {
      int brq = 0 * HDIM + 16 * n + lane15;
      int bpq = lhi ^ ((brq >> 1) & 3);
      bf16x8 bq = __builtin_bit_cast(bf16x8,
          *reinterpret_cast<const u16x8*>(wsb + brq * 32 + bpq * 8));
      int brk = 1 * HDIM + 16 * n + lane15;
      int bpk = lhi ^ ((brk >> 1) & 3);
      bf16x8 bk = __builtin_bit_cast(bf16x8,
          *reinterpret_cast<const u16x8*>(wsb + brk * 32 + bpk * 8));
      int brv = 2 * HDIM + 16 * n + lane15;
      int bpv = lhi ^ ((brv >> 1) & 3);
      bf16x8 bv = __builtin_bit_cast(bf16x8,
          *reinterpret_cast<const u16x8*>(wsb + brv * 32 + bpv * 8));
      accq[0][n] = mfma16(a0, bq, accq[0][n]);
      acck[0][n] = mfma16(a0, bk, acck[0][n]);
      accv[0][n] = mfma16(a0, bv, accv[0][n]);
      accq[1][n] = mfma16(a1, bq, accq[1][n]);
      acck[1][n] = mfma16(a1, bk, acck[1][n]);
      accv[1][n] = mfma16(a1, bv, accv[1][n]);
      accq[2][n] = mfma16(a2, bq, accq[2][n]);
      acck[2][n] = mfma16(a2, bk, acck[2][n]);
      accv[2][n] = mfma16(a2, bv, accv[2][n]);
      accq[3][n] = mfma16(a3, bq, accq[3][n]);
      acck[3][n] = mfma16(a3, bk, acck[3][n]);
      accv[3][n] = mfma16(a3, bv, accv[3][n]);
    }

    asm volatile("s_waitcnt lgkmcnt(0)" ::: "memory");
    __builtin_amdgcn_s_barrier();

    if (c + 2 < NCHUNK) { STAGE_W(c + 2, c & 1); STAGE_X(c + 2, c & 1); }
  }

  #undef STAGE_X
  #undef STAGE_W

  // ---- epilogue: 4 rounds; round s handles local batches {2s, 2s+1} --------
  unsigned short* k_lds  = (unsigned short*)((char*)smem + bat * 24576);
  unsigned short* vT_lds = (unsigned short*)((char*)smem + bat * 24576 + 8192);
  unsigned short* qp_lds = (unsigned short*)((char*)smem + bat * 24576 + 16384);
  const int trow = 16 * ww + lane15;
  float* outbase = out + (size_t)(PB * bid + bat) * (SEQ * HDIM);

  #pragma unroll
  for (int s = 0; s < 4; ++s) {
    // park slice s: k, vT, q as bf16 swizzled
    // C/D layout: col = lane&15, row = (lane>>4)*4 + j   [measured m89/m91]
    #pragma unroll
    for (int n = 0; n < 4; ++n) {
      int h = 16 * n + lane15;
      #pragma unroll
      for (int j = 0; j < 4; ++j) {
        int srow = 16 * ww + lhi * 4 + j;
        k_lds[swz(srow, h)] = f2bf(acck[s][n][j]);
        vT_lds[swz(h, srow)] = f2bf(accv[s][n][j]);
        qp_lds[swz(srow, h)] = f2bf(accq[s][n][j]);
      }
    }
    __syncthreads();

    // phase 2: S = q k^T
    bf16x8 aq0 = lds_frag(qp_lds, trow, lhi * 8);
    bf16x8 aq1 = lds_frag(qp_lds, trow, 32 + lhi * 8);
    f32x4v accS[4];
    #pragma unroll
    for (int n = 0; n < 4; ++n) accS[n] = z4;
    #pragma unroll
    for (int sB = 0; sB < 4; ++sB) {
      if (sB <= ww) {
        bf16x8 bk0 = lds_frag(k_lds, 16 * sB + lane15, lhi * 8);
        bf16x8 bk1 = lds_frag(k_lds, 16 * sB + lane15, 32 + lhi * 8);
        accS[sB] = mfma16(aq0, bk0, accS[sB]);
        accS[sB] = mfma16(aq1, bk1, accS[sB]);
      }
    }

    // phase 3: fp32 causal softmax, P -> bf16 LDS
    float rinv[4];
    #pragma unroll
    for (int j = 0; j < 4; ++j) {
      int t = 16 * ww + lhi * 4 + j;
      float zv[4];
      float m = -3.0e38f;
      #pragma unroll
      for (int sB = 0; sB < 4; ++sB) {
        int sc = 16 * sB + lane15;
        float zz = (sB <= ww && sc <= t) ? accS[sB][j] * 0.125f : -3.0e38f;
        zv[sB] = zz;
        m = fmaxf(m, zz);
      }
      #pragma unroll
      for (int off = 1; off < 16; off <<= 1) m = fmaxf(m, __shfl_xor(m, off));
      float sum = 0.f;
      float pv[4];
      #pragma unroll
      for (int sB = 0; sB < 4; ++sB) {
        float pe = __expf(zv[sB] - m);
        pv[sB] = pe;
        sum += pe;
      }
      #pragma unroll
      for (int off = 1; off < 16; off <<= 1) sum += __shfl_xor(sum, off);
      rinv[j] = 1.0f / sum;
      #pragma unroll
      for (int sB = 0; sB < 4; ++sB)
        qp_lds[swz(t, 16 * sB + lane15)] = f2bf(pv[sB]);
    }
    __syncthreads();

    // phase 4: O = P V
    f32x4v accO[4];
    #pragma unroll
    for (int n = 0; n < 4; ++n) accO[n] = z4;
    #pragma unroll
    for (int s0 = 0; s0 < 64; s0 += 32) {
      if (s0 <= 16 * ww + 15) {
        bf16x8 ap = lds_frag(qp_lds, trow, s0 + lhi * 8);
        #pragma unroll
        for (int n = 0; n < 4; ++n) {
          bf16x8 bv = lds_frag(vT_lds, 16 * n + lane15, s0 + lhi * 8);
          accO[n] = mfma16(ap, bv, accO[n]);
        }
      }
    }

    // phase 5: normalize + store fp32
    float* op = outbase + (size_t)(2 * s) * (SEQ * HDIM);
    #pragma unroll
    for (int n = 0; n < 4; ++n) {
      int h = 16 * n + lane15;
      #pragma unroll
      for (int j = 0; j < 4; ++j) {
        int t = 16 * ww + lhi * 4 + j;
        op[t * HDIM + h] = accO[n][j] * rinv[j];
      }
    }
    __syncthreads();  // LDS reads done before next round's parking overwrites
  }
}

extern "C" void kernel_launch(void* const* d_in, const int* in_sizes, int n_in,
                              void* d_out, int out_size, void* d_ws, size_t ws_size,
                              hipStream_t stream) {
  const float* x  = (const float*)d_in[0];
  const float* Wk = (const float*)d_in[1];
  const float* Wq = (const float*)d_in[2];
  const float* Wv = (const float*)d_in[3];
  float* out = (float*)d_out;
  unsigned short* wt = (unsigned short*)d_ws;  // 24 chunks x 12 KB = 288 KiB

  hipLaunchKernelGGL(prep_wt_kernel, dim3((3 * HDIM * CDIM + 255) / 256), dim3(256),
                     0, stream, Wk, Wq, Wv, wt);
  hipLaunchKernelGGL(head_fused_kernel, dim3(BATCHES / PB), dim3(512), 0, stream,
                     x, wt, out);
}

// Round 8
// 107.669 us; speedup vs baseline: 1.1416x; 1.1416x over previous
//
#include <hip/hip_runtime.h>

// Single-head causal attention. Round 8: BK=64 x-chunks (256B/row-visit for
// DRAM page locality), wt held in registers (col-split across waves, loaded
// 1 iter ahead from L2, zero wt LDS/DMA), 64 KB LDS -> 2 blocks/CU.
// B=2048, T=64, C=768, H=64. Inputs fp32: x, Wk, Wq, Wv ([in,out] layout).

#define BATCHES 2048
#define SEQ 64
#define CDIM 768
#define HDIM 64
#define NCX 12  // 768 / 64

typedef __bf16 bf16x8 __attribute__((ext_vector_type(8)));
typedef float f32x4v __attribute__((ext_vector_type(4)));
typedef unsigned short u16x8 __attribute__((ext_vector_type(8)));

__device__ __forceinline__ unsigned short f2bf(float f) {
  return __builtin_bit_cast(unsigned short, (__bf16)f);
}

// XOR swizzle for 64-elem bf16 parking rows: elem col ^= ((row&7)<<3)
__device__ __forceinline__ int swz(int row, int col) {
  return row * 64 + (col ^ ((row & 7) << 3));
}

__device__ __forceinline__ f32x4v mfma16(bf16x8 a, bf16x8 b, f32x4v c) {
  return __builtin_amdgcn_mfma_f32_16x16x32_bf16(a, b, c, 0, 0, 0);
}

__device__ __forceinline__ bf16x8 lds_frag(const unsigned short* p, int row, int col) {
  return __builtin_bit_cast(bf16x8, *reinterpret_cast<const u16x8*>(p + swz(row, col)));
}

__device__ __forceinline__ void gl_lds16(const void* g, void* l) {
  __builtin_amdgcn_global_load_lds(
      (const __attribute__((address_space(1))) void*)g,
      (__attribute__((address_space(3))) void*)l, 16, 0, 0);
}

// Prep: wt[S][f][lane][e], S=32-col chunk 0..23, f=mat*4+n (0..11), lane 0..63,
// e 0..7: element = W_mat[k=S*32+(lane>>4)*8+e][h=16*n+(lane&15)].
// Each (S,f) is a 1KB contiguous per-wave B-fragment load.
__global__ __launch_bounds__(256) void prep_wt_kernel(
    const float* __restrict__ Wk, const float* __restrict__ Wq,
    const float* __restrict__ Wv, unsigned short* __restrict__ wt) {
  int i = blockIdx.x * 256 + threadIdx.x;
  if (i >= 24 * 6144) return;
  int S = i / 6144;
  int r = i - S * 6144;
  int f = r >> 9;
  int lane = (r >> 3) & 63;
  int e = r & 7;
  int mat = f >> 2;
  int n = f & 3;
  int h = 16 * n + (lane & 15);
  int k = S * 32 + (lane >> 4) * 8 + e;
  const float* W = (mat == 0) ? Wq : ((mat == 1) ? Wk : Wv);
  wt[i] = f2bf(W[k * HDIM + h]);
}

__global__ __launch_bounds__(256, 2) void head_fused_kernel(
    const float* __restrict__ x, const unsigned short* __restrict__ wt,
    float* __restrict__ out) {
  const int bid = blockIdx.x;        // batches 2*bid, 2*bid+1
  const int tid = threadIdx.x;
  const int w = tid >> 6;            // wave 0..3: owns col-frags n=w (all mats)
  const int lane = tid & 63;
  const int lane15 = lane & 15;
  const int lhi = lane >> 4;

  // LDS 64 KB: x dbuf 2 x 32 KB. Buffer: [batch 0: 16K][batch 1: 16K];
  // per batch: [row 0..63][granule 0..15]x16B, source-swizzled g^=(row&15).
  // Parking (after streaming) aliases buf0: [k 8K][vT 8K][qp 8K].
  __shared__ __align__(16) unsigned char smem[65536];

  #define STAGE_X(cn, B)                                                     \
    do {                                                                     \
      char* xbp = (char*)smem + (B) * 32768;                                 \
      _Pragma("unroll")                                                      \
      for (int i = 0; i < 8; ++i) {                                          \
        int slot = i * 256 + tid;                                            \
        int batch = slot >> 10, rem = slot & 1023;                           \
        int row = rem >> 4, g = rem & 15;                                    \
        gl_lds16((const char*)x + (size_t)(2 * bid + batch) * 196608 +       \
                     row * 3072 + (cn) * 256 + ((g ^ (row & 15)) * 16),      \
                 xbp + slot * 16);                                           \
      }                                                                      \
    } while (0)

  // Load 2 sub-chunks (S0, S0+1) of this wave's 3 col-frags into DST[6].
  #define ISSUE_WT(S0, DST)                                                  \
    do {                                                                     \
      _Pragma("unroll")                                                      \
      for (int kk = 0; kk < 2; ++kk)                                         \
        _Pragma("unroll")                                                    \
        for (int j = 0; j < 3; ++j)                                          \
          DST[kk * 3 + j] = __builtin_bit_cast(bf16x8,                       \
              *reinterpret_cast<const u16x8*>(                               \
                  wt + ((S0) + kk) * 6144 + (j * 4 + w) * 512 + lane * 8));  \
    } while (0)

  const f32x4v z4 = {0.f, 0.f, 0.f, 0.f};
  f32x4v accq[2][4], acck[2][4], accv[2][4];  // [batch][rowgroup]
  #pragma unroll
  for (int b2 = 0; b2 < 2; ++b2)
    #pragma unroll
    for (int rg = 0; rg < 4; ++rg) { accq[b2][rg] = z4; acck[b2][rg] = z4; accv[b2][rg] = z4; }

  #define COMPUTE(c, CUR)                                                    \
    do {                                                                     \
      const char* xb = (const char*)smem + ((c) & 1) * 32768;                \
      _Pragma("unroll")                                                      \
      for (int kk = 0; kk < 2; ++kk) {                                       \
        _Pragma("unroll")                                                    \
        for (int bb = 0; bb < 2; ++bb) {                                     \
          _Pragma("unroll")                                                  \
          for (int rg = 0; rg < 4; ++rg) {                                   \
            int row = rg * 16 + lane15;                                      \
            const char* base = xb + bb * 16384 + row * 256;                  \
            int g0 = (kk * 8 + lhi * 2) ^ (row & 15);                        \
            int g1 = (kk * 8 + lhi * 2 + 1) ^ (row & 15);                    \
            f32x4v xa = *(const f32x4v*)(base + g0 * 16);                    \
            f32x4v xc = *(const f32x4v*)(base + g1 * 16);                    \
            u16x8 ar;                                                        \
            _Pragma("unroll")                                                \
            for (int i = 0; i < 4; ++i) { ar[i] = f2bf(xa[i]); ar[4 + i] = f2bf(xc[i]); } \
            bf16x8 a = __builtin_bit_cast(bf16x8, ar);                       \
            accq[bb][rg] = mfma16(a, CUR[kk * 3 + 0], accq[bb][rg]);         \
            acck[bb][rg] = mfma16(a, CUR[kk * 3 + 1], acck[bb][rg]);         \
            accv[bb][rg] = mfma16(a, CUR[kk * 3 + 2], accv[bb][rg]);         \
          }                                                                  \
        }                                                                    \
      }                                                                      \
    } while (0)

  // Per-iter: [issue wt for c+1 | fence | vmcnt(CNT) for x(c) | fence |
  // barrier | compute | lgkm+fence+barrier | stage x(c+2) | fence]
  #define ITER(c, CUR, NXT, CNT)                                             \
    do {                                                                     \
      if ((c) <= 10) ISSUE_WT(2 * (c) + 2, NXT);                             \
      __builtin_amdgcn_sched_barrier(0);                                     \
      asm volatile("s_waitcnt vmcnt(" #CNT ")" ::: "memory");                \
      __builtin_amdgcn_sched_barrier(0);                                     \
      __builtin_amdgcn_s_barrier();                                          \
      COMPUTE(c, CUR);                                                       \
      asm volatile("s_waitcnt lgkmcnt(0)" ::: "memory");                     \
      __builtin_amdgcn_sched_barrier(0);                                     \
      __builtin_amdgcn_s_barrier();                                          \
      if ((c) + 2 < NCX) STAGE_X((c) + 2, (c) & 1);                          \
      __builtin_amdgcn_sched_barrier(0);                                     \
    } while (0)

  bf16x8 U[6], V[6];

  // prologue: wt(0,1) -> U, then x(0) -> buf0, x(1) -> buf1
  ISSUE_WT(0, U);
  __builtin_amdgcn_sched_barrier(0);
  STAGE_X(0, 0);
  STAGE_X(1, 1);
  __builtin_amdgcn_sched_barrier(0);

  // Derived x-waits (newer-than-x(c) issue counts, order pinned by fences):
  // c=0: x(1)8 + wtV6 = 14; c=1..10: wt6 + x8 + wt6 = 20; c=11: wt6 = 6.
  ITER(0, U, V, 14);
  ITER(1, V, U, 20);
  ITER(2, U, V, 20);
  ITER(3, V, U, 20);
  ITER(4, U, V, 20);
  ITER(5, V, U, 20);
  ITER(6, U, V, 20);
  ITER(7, V, U, 20);
  ITER(8, U, V, 20);
  ITER(9, V, U, 20);
  ITER(10, U, V, 20);
  ITER(11, V, U, 6);

  #undef ITER
  #undef COMPUTE
  #undef ISSUE_WT
  #undef STAGE_X

  // ---- epilogue: 2 rounds, round s = batch 2*bid+s --------------------------
  unsigned short* k_lds  = (unsigned short*)smem;
  unsigned short* vT_lds = (unsigned short*)(smem + 8192);
  unsigned short* qp_lds = (unsigned short*)(smem + 16384);
  const int trow = 16 * w + lane15;

  #pragma unroll
  for (int s = 0; s < 2; ++s) {
    // park: wave w holds h-columns [16w,16w+16) for all rows.
    // C/D layout: col = lane&15, row = (lane>>4)*4 + j   [measured m89/m91]
    #pragma unroll
    for (int rg = 0; rg < 4; ++rg) {
      int h = 16 * w + lane15;
      #pragma unroll
      for (int j = 0; j < 4; ++j) {
        int srow = rg * 16 + lhi * 4 + j;
        k_lds[swz(srow, h)] = f2bf(acck[s][rg][j]);
        vT_lds[swz(h, srow)] = f2bf(accv[s][rg][j]);
        qp_lds[swz(srow, h)] = f2bf(accq[s][rg][j]);
      }
    }
    __syncthreads();

    // phase 2: S = q k^T (wave w owns Q-rows [16w,16w+16))
    bf16x8 aq0 = lds_frag(qp_lds, trow, lhi * 8);
    bf16x8 aq1 = lds_frag(qp_lds, trow, 32 + lhi * 8);
    f32x4v accS[4];
    #pragma unroll
    for (int n = 0; n < 4; ++n) accS[n] = z4;
    #pragma unroll
    for (int sB = 0; sB < 4; ++sB) {
      if (sB <= w) {
        bf16x8 bk0 = lds_frag(k_lds, 16 * sB + lane15, lhi * 8);
        bf16x8 bk1 = lds_frag(k_lds, 16 * sB + lane15, 32 + lhi * 8);
        accS[sB] = mfma16(aq0, bk0, accS[sB]);
        accS[sB] = mfma16(aq1, bk1, accS[sB]);
      }
    }

    // phase 3: fp32 causal softmax, P -> bf16 LDS
    float rinv[4];
    #pragma unroll
    for (int j = 0; j < 4; ++j) {
      int t = 16 * w + lhi * 4 + j;
      float zv[4];
      float m = -3.0e38f;
      #pragma unroll
      for (int sB = 0; sB < 4; ++sB) {
        int sc = 16 * sB + lane15;
        float zz = (sB <= w && sc <= t) ? accS[sB][j] * 0.125f : -3.0e38f;
        zv[sB] = zz;
        m = fmaxf(m, zz);
      }
      #pragma unroll
      for (int off = 1; off < 16; off <<= 1) m = fmaxf(m, __shfl_xor(m, off));
      float sum = 0.f;
      float pv[4];
      #pragma unroll
      for (int sB = 0; sB < 4; ++sB) {
        float pe = __expf(zv[sB] - m);
        pv[sB] = pe;
        sum += pe;
      }
      #pragma unroll
      for (int off = 1; off < 16; off <<= 1) sum += __shfl_xor(sum, off);
      rinv[j] = 1.0f / sum;
      #pragma unroll
      for (int sB = 0; sB < 4; ++sB)
        qp_lds[swz(t, 16 * sB + lane15)] = f2bf(pv[sB]);
    }
    __syncthreads();

    // phase 4: O = P V
    f32x4v accO[4];
    #pragma unroll
    for (int n = 0; n < 4; ++n) accO[n] = z4;
    #pragma unroll
    for (int s0 = 0; s0 < 64; s0 += 32) {
      if (s0 <= 16 * w + 15) {
        bf16x8 ap = lds_frag(qp_lds, trow, s0 + lhi * 8);
        #pragma unroll
        for (int n = 0; n < 4; ++n) {
          bf16x8 bv = lds_frag(vT_lds, 16 * n + lane15, s0 + lhi * 8);
          accO[n] = mfma16(ap, bv, accO[n]);
        }
      }
    }

    // phase 5: normalize + store fp32
    float* op = out + (size_t)(2 * bid + s) * (SEQ * HDIM);
    #pragma unroll
    for (int n = 0; n < 4; ++n) {
      int h = 16 * n + lane15;
      #pragma unroll
      for (int j = 0; j < 4; ++j) {
        int t = 16 * w + lhi * 4 + j;
        op[t * HDIM + h] = accO[n][j] * rinv[j];
      }
    }
    __syncthreads();  // LDS reads done before next round's parking overwrites
  }
}

extern "C" void kernel_launch(void* const* d_in, const int* in_sizes, int n_in,
                              void* d_out, int out_size, void* d_ws, size_t ws_size,
                              hipStream_t stream) {
  const float* x  = (const float*)d_in[0];
  const float* Wk = (const float*)d_in[1];
  const float* Wq = (const float*)d_in[2];
  const float* Wv = (const float*)d_in[3];
  float* out = (float*)d_out;
  unsigned short* wt = (unsigned short*)d_ws;  // 24 x 12 KB = 288 KiB

  hipLaunchKernelGGL(prep_wt_kernel, dim3((24 * 6144 + 255) / 256), dim3(256),
                     0, stream, Wk, Wq, Wv, wt);
  hipLaunchKernelGGL(head_fused_kernel, dim3(BATCHES / 2), dim3(256), 0, stream,
                     x, wt, out);
}